// Round 5
// baseline (475.032 us; speedup 1.0000x reference)
//
#include <hip/hip_runtime.h>
#include <hip/hip_bf16.h>
#include <stdint.h>

#define NCLOTHES 50000
#define CPAD     50048   // 391 * 128
#define NCB2     782     // 64-col tiles (one per wave quadrant column)
#define FDIM     256
#define NBATCH   1024
#define SCALEF   16.0f
#define EPSW     0.1f
#define SLOTS    8       // positive slots per (row, 64-col tile); lambda=0.64

typedef __attribute__((ext_vector_type(8))) short short8;
typedef __attribute__((ext_vector_type(4))) float f32x4;

// inputs_norm * SCALE -> bf16 A [1024][256]; one block (256 thr) per row
__global__ void anorm_kernel(const float* __restrict__ in, __hip_bfloat16* __restrict__ A) {
    int b = blockIdx.x, t = threadIdx.x;
    float x = in[b * FDIM + t];
    float ss = x * x;
    #pragma unroll
    for (int o = 32; o > 0; o >>= 1) ss += __shfl_xor(ss, o);
    __shared__ float sh[4];
    if ((t & 63) == 0) sh[t >> 6] = ss;
    __syncthreads();
    float tot = sh[0] + sh[1] + sh[2] + sh[3];
    float r = SCALEF / fmaxf(sqrtf(tot), 1e-12f);
    A[b * FDIM + t] = __float2bfloat16(x * r);
}

// normalize ALL feature_memory rows -> bf16 B; wave-per-row streaming, grid-stride
__global__ __launch_bounds__(256)
void bnorm_all(const float* __restrict__ fm, __hip_bfloat16* __restrict__ Bm) {
    const int nw = (gridDim.x * 256) >> 6;
    int w = (blockIdx.x * 256 + threadIdx.x) >> 6;
    int lane = threadIdx.x & 63;
    for (int row = w; row < CPAD; row += nw) {
        __hip_bfloat16 h[4];
        if (row >= NCLOTHES) {
            h[0] = h[1] = h[2] = h[3] = __float2bfloat16(0.f);
        } else {
            f32x4 v = *(const f32x4*)(fm + (size_t)row * FDIM + lane * 4);
            float ss = v.x * v.x + v.y * v.y + v.z * v.z + v.w * v.w;
            #pragma unroll
            for (int o = 32; o > 0; o >>= 1) ss += __shfl_xor(ss, o);
            float r = 1.f / fmaxf(sqrtf(ss), 1e-12f);
            h[0] = __float2bfloat16(v.x * r);
            h[1] = __float2bfloat16(v.y * r);
            h[2] = __float2bfloat16(v.z * r);
            h[3] = __float2bfloat16(v.w * r);
        }
        *(ushort4*)(Bm + (size_t)row * FDIM + lane * 4) = *(const ushort4*)h;
    }
}

// overwrite the <=1024 present clothes rows with normalized scatter-mean
__global__ void bnorm_present(const float* __restrict__ in, const int* __restrict__ tg,
                              __hip_bfloat16* __restrict__ Bm) {
    int b = blockIdx.x, t = threadIdx.x;
    __shared__ int stg[NBATCH];
    #pragma unroll
    for (int j = 0; j < 4; ++j) stg[t + j * 256] = tg[t + j * 256];
    __syncthreads();
    int c = stg[b];
    bool dup = false;
    #pragma unroll
    for (int j = 0; j < 4; ++j) {
        int i = t + j * 256;
        if (i < b && stg[i] == c) dup = true;
    }
    if (__syncthreads_or(dup)) return;
    __shared__ int mlist[64];
    __shared__ int mcount;
    if (t == 0) mcount = 0;
    __syncthreads();
    #pragma unroll
    for (int j = 0; j < 4; ++j) {
        int i = t + j * 256;
        if (stg[i] == c) { int p = atomicAdd(&mcount, 1); if (p < 64) mlist[p] = i; }
    }
    __syncthreads();
    int n = mcount;
    float v = 0.f;
    for (int i = 0; i < n; ++i) v += in[mlist[i] * FDIM + t];
    v /= (float)n;
    float ss = v * v;
    #pragma unroll
    for (int o = 32; o > 0; o >>= 1) ss += __shfl_xor(ss, o);
    __shared__ float sh[4];
    if ((t & 63) == 0) sh[t >> 6] = ss;
    __syncthreads();
    float tot = sh[0] + sh[1] + sh[2] + sh[3];
    float r = 1.0f / fmaxf(sqrtf(tot), 1e-12f);
    Bm[(size_t)c * FDIM + t] = __float2bfloat16(v * r);
}

// No-LDS, no-barrier fused GEMM. Each wave owns a 64x64 quadrant:
// A/B fragments loaded direct from global (A: L2-resident, B: L3-resident).
// pm prefetched across the K-loop; epilogue: exp/neg-sum/ballot-slots, no atomics.
__global__ __launch_bounds__(256, 3)
void gemm_kernel(const __hip_bfloat16* __restrict__ A, const __hip_bfloat16* __restrict__ Bm,
                 const float* __restrict__ pm,
                 float* __restrict__ partial_ns,      // [NBATCH][NCB2]
                 unsigned int* __restrict__ cnt,      // [NBATCH][NCB2]
                 float* __restrict__ sbuf,            // [NBATCH][NCB2][SLOTS]
                 unsigned char* __restrict__ colbuf)  // [NBATCH][NCB2][SLOTS], local col 0..63
{
    const int t = threadIdx.x;
    const int lane = t & 63;
    const int wave = t >> 6;
    const int wr = wave >> 1, wc = wave & 1;
    const int lrow = lane & 15, lq = lane >> 4;

    const int rowbase = blockIdx.y * 128 + wr * 64;   // wave's first output row
    const int colbase = blockIdx.x * 128 + wc * 64;   // wave's first output col
    const int cb2 = blockIdx.x * 2 + wc;

    const float* pmw = pm + (size_t)rowbase * NCLOTHES + colbase;
    const __hip_bfloat16* Ab = A  + (size_t)rowbase * FDIM + lq * 8;
    const __hip_bfloat16* Bb = Bm + (size_t)colbase * FDIM + lq * 8;

    // column validity per n (same for all loads of this thread)
    bool vld[4];
    #pragma unroll
    for (int n = 0; n < 4; ++n) vld[n] = (colbase + n * 16 + lrow) < NCLOTHES;

    // ---- prefetch pm for m=0 rows (hidden under K-loop) ----
    float pv0[4][4];   // [r][n]
    #pragma unroll
    for (int r = 0; r < 4; ++r)
        #pragma unroll
        for (int n = 0; n < 4; ++n)
            pv0[r][n] = vld[n] ? pmw[(size_t)(lq * 4 + r) * NCLOTHES + n * 16 + lrow] : 0.f;

    // ---- K-loop: direct-from-global fragments, no barriers ----
    f32x4 acc[4][4];
    #pragma unroll
    for (int m = 0; m < 4; ++m)
        #pragma unroll
        for (int n = 0; n < 4; ++n) acc[m][n] = (f32x4)0.f;

    #pragma unroll 2
    for (int ks = 0; ks < FDIM / 32; ++ks) {
        short8 af[4], bf[4];
        #pragma unroll
        for (int m = 0; m < 4; ++m)
            af[m] = *(const short8*)(Ab + (size_t)(m * 16 + lrow) * FDIM + ks * 32);
        #pragma unroll
        for (int n = 0; n < 4; ++n)
            bf[n] = *(const short8*)(Bb + (size_t)(n * 16 + lrow) * FDIM + ks * 32);
        #pragma unroll
        for (int m = 0; m < 4; ++m)
            #pragma unroll
            for (int n = 0; n < 4; ++n)
                acc[m][n] = __builtin_amdgcn_mfma_f32_16x16x32_bf16(af[m], bf[n], acc[m][n], 0, 0, 0);
    }

    // ---- issue remaining pm loads (m=1..3) in one burst, then consume ----
    float pv1[4][4], pv2[4][4], pv3[4][4];
    #pragma unroll
    for (int r = 0; r < 4; ++r)
        #pragma unroll
        for (int n = 0; n < 4; ++n) {
            int col = n * 16 + lrow;
            pv1[r][n] = vld[n] ? pmw[(size_t)(16 + lq * 4 + r) * NCLOTHES + col] : 0.f;
            pv2[r][n] = vld[n] ? pmw[(size_t)(32 + lq * 4 + r) * NCLOTHES + col] : 0.f;
            pv3[r][n] = vld[n] ? pmw[(size_t)(48 + lq * 4 + r) * NCLOTHES + col] : 0.f;
        }

    #pragma unroll
    for (int m = 0; m < 4; ++m) {
        #pragma unroll
        for (int r = 0; r < 4; ++r) {
            const int grow = rowbase + m * 16 + lq * 4 + r;
            float pneg = 0.f;
            unsigned posn = 0;
            #pragma unroll
            for (int n = 0; n < 4; ++n) {
                float pmv = (m == 0) ? pv0[r][n] : (m == 1) ? pv1[r][n] : (m == 2) ? pv2[r][n] : pv3[r][n];
                bool pos = vld[n] && (pmv >= 0.5f);
                if (pos) posn |= (1u << n);
                pneg += (vld[n] && !pos) ? __expf(acc[m][n][r]) : 0.f;
            }
            pneg += __shfl_xor(pneg, 1);
            pneg += __shfl_xor(pneg, 2);
            pneg += __shfl_xor(pneg, 4);
            pneg += __shfl_xor(pneg, 8);
            const size_t idx = (size_t)grow * NCB2 + cb2;
            int slot_base = 0;
            #pragma unroll
            for (int n = 0; n < 4; ++n) {
                unsigned long long bal = __ballot((posn >> n) & 1);
                unsigned seg = (unsigned)((bal >> (lq * 16)) & 0xFFFFull);
                int pre = slot_base + __popc(seg & ((1u << lrow) - 1u));
                if (((posn >> n) & 1) && pre < SLOTS) {
                    sbuf[idx * SLOTS + pre] = acc[m][n][r];
                    colbuf[idx * SLOTS + pre] = (unsigned char)(n * 16 + lrow);
                }
                slot_base += __popc(seg);
            }
            if (lrow == 0) {
                cnt[idx] = (unsigned int)(slot_base < SLOTS ? slot_base : SLOTS);
                partial_ns[idx] = pneg;
            }
        }
    }
}

__global__ void finish_kernel(const float* __restrict__ partial_ns, const unsigned int* __restrict__ cnt,
                              const float* __restrict__ sbuf, const unsigned char* __restrict__ colbuf,
                              const int* __restrict__ tg, float* __restrict__ loss_rows) {
    int b = blockIdx.x, t = threadIdx.x;
    int tgt = tg[b];
    float ns = 0.f;
    int np = 0;
    for (int cb = t; cb < NCB2; cb += 256) {
        size_t idx = (size_t)b * NCB2 + cb;
        ns += partial_ns[idx];
        np += (int)cnt[idx];
    }
    #pragma unroll
    for (int o = 32; o > 0; o >>= 1) { ns += __shfl_xor(ns, o); np += __shfl_xor(np, o); }
    __shared__ float shn[4]; __shared__ int shp[4];
    if ((t & 63) == 0) { shn[t >> 6] = ns; shp[t >> 6] = np; }
    __syncthreads();
    ns = shn[0] + shn[1] + shn[2] + shn[3];
    np = shp[0] + shp[1] + shp[2] + shp[3];

    float slp = 0.f, idlp = 0.f;
    for (int cb = t; cb < NCB2; cb += 256) {
        size_t idx = (size_t)b * NCB2 + cb;
        int k = (int)cnt[idx];
        for (int i = 0; i < k; ++i) {
            float s = sbuf[idx * SLOTS + i];
            int col = cb * 64 + (int)colbuf[idx * SLOTS + i];
            float lp = s - __logf(ns + __expf(s));
            slp += lp;
            if (col == tgt) idlp += lp;
        }
    }
    #pragma unroll
    for (int o = 32; o > 0; o >>= 1) { slp += __shfl_xor(slp, o); idlp += __shfl_xor(idlp, o); }
    __shared__ float sh1[4], sh2[4];
    if ((t & 63) == 0) { sh1[t >> 6] = slp; sh2[t >> 6] = idlp; }
    __syncthreads();
    if (t == 0) {
        float s_all = sh1[0] + sh1[1] + sh1[2] + sh1[3];
        float i_all = sh2[0] + sh2[1] + sh2[2] + sh2[3];
        loss_rows[b] = -((1.0f - EPSW) * i_all + (EPSW / (float)np) * s_all);
    }
}

__global__ void reduce_kernel(const float* __restrict__ lr, float* __restrict__ out) {
    int t = threadIdx.x;
    float s = lr[t] + lr[t + 256] + lr[t + 512] + lr[t + 768];
    #pragma unroll
    for (int o = 32; o > 0; o >>= 1) s += __shfl_xor(s, o);
    __shared__ float sh[4];
    if ((t & 63) == 0) sh[t >> 6] = s;
    __syncthreads();
    if (t == 0) out[0] = (sh[0] + sh[1] + sh[2] + sh[3]) * (1.0f / NBATCH);
}

extern "C" void kernel_launch(void* const* d_in, const int* in_sizes, int n_in,
                              void* d_out, int out_size, void* d_ws, size_t ws_size,
                              hipStream_t stream) {
    const float* inputs  = (const float*)d_in[0];
    const float* fm      = (const float*)d_in[1];
    const float* pmask   = (const float*)d_in[2];
    const int*   targets = (const int*)d_in[3];
    float* out = (float*)d_out;

    char* ws = (char*)d_ws;
    size_t off = 0;
    __hip_bfloat16* A = (__hip_bfloat16*)(ws + off);  off += (size_t)NBATCH * FDIM * 2;        // 512 KB
    __hip_bfloat16* Bm = (__hip_bfloat16*)(ws + off); off += (size_t)CPAD * FDIM * 2;          // 25.6 MB
    off = (off + 255) & ~(size_t)255;
    float* partial_ns = (float*)(ws + off);        off += (size_t)NBATCH * NCB2 * 4;           // 3.2 MB
    unsigned int* cnt = (unsigned int*)(ws + off); off += (size_t)NBATCH * NCB2 * 4;           // 3.2 MB
    float* sbuf = (float*)(ws + off);              off += (size_t)NBATCH * NCB2 * SLOTS * 4;   // 25.6 MB
    unsigned char* colbuf = (unsigned char*)(ws + off); off += (size_t)NBATCH * NCB2 * SLOTS;  // 6.4 MB
    off = (off + 255) & ~(size_t)255;
    float* loss_rows = (float*)(ws + off);         off += 4096;

    anorm_kernel<<<NBATCH, 256, 0, stream>>>(inputs, A);
    bnorm_all<<<2048, 256, 0, stream>>>(fm, Bm);
    bnorm_present<<<NBATCH, 256, 0, stream>>>(inputs, targets, Bm);
    gemm_kernel<<<dim3(CPAD / 128, NBATCH / 128), 256, 0, stream>>>(A, Bm, pmask, partial_ns, cnt, sbuf, colbuf);
    finish_kernel<<<NBATCH, 256, 0, stream>>>(partial_ns, cnt, sbuf, colbuf, targets, loss_rows);
    reduce_kernel<<<1, 256, 0, stream>>>(loss_rows, out);
}

// Round 6
// 469.104 us; speedup vs baseline: 1.0126x; 1.0126x over previous
//
#include <hip/hip_runtime.h>
#include <hip/hip_bf16.h>
#include <stdint.h>

#define NCLOTHES 50000
#define CPAD     50048   // 391 * 128
#define NWORDS   782     // 64-col mask words per row (== NCB2)
#define NCB2     782
#define FDIM     256
#define NBATCH   1024
#define SCALEF   16.0f
#define EPSW     0.1f
#define SLOTS    8       // positive slots per (row, 64-col word); lambda=0.64

typedef __attribute__((ext_vector_type(8))) short short8;
typedef __attribute__((ext_vector_type(4))) float f32x4;

__device__ __forceinline__ void gload_lds16(const void* gsrc, void* ldst) {
    __builtin_amdgcn_global_load_lds(
        (const __attribute__((address_space(1))) void*)gsrc,
        (__attribute__((address_space(3))) void*)ldst, 16, 0, 0);
}

// inputs_norm * SCALE -> bf16 A [1024][256]
__global__ void anorm_kernel(const float* __restrict__ in, __hip_bfloat16* __restrict__ A) {
    int b = blockIdx.x, t = threadIdx.x;
    float x = in[b * FDIM + t];
    float ss = x * x;
    #pragma unroll
    for (int o = 32; o > 0; o >>= 1) ss += __shfl_xor(ss, o);
    __shared__ float sh[4];
    if ((t & 63) == 0) sh[t >> 6] = ss;
    __syncthreads();
    float tot = sh[0] + sh[1] + sh[2] + sh[3];
    float r = SCALEF / fmaxf(sqrtf(tot), 1e-12f);
    A[b * FDIM + t] = __float2bfloat16(x * r);
}

// normalize ALL feature_memory rows -> bf16 B; wave-per-row streaming
__global__ __launch_bounds__(256)
void bnorm_all(const float* __restrict__ fm, __hip_bfloat16* __restrict__ Bm) {
    const int nw = (gridDim.x * 256) >> 6;
    int w = (blockIdx.x * 256 + threadIdx.x) >> 6;
    int lane = threadIdx.x & 63;
    for (int row = w; row < CPAD; row += nw) {
        __hip_bfloat16 h[4];
        if (row >= NCLOTHES) {
            h[0] = h[1] = h[2] = h[3] = __float2bfloat16(0.f);
        } else {
            f32x4 v = *(const f32x4*)(fm + (size_t)row * FDIM + lane * 4);
            float ss = v.x * v.x + v.y * v.y + v.z * v.z + v.w * v.w;
            #pragma unroll
            for (int o = 32; o > 0; o >>= 1) ss += __shfl_xor(ss, o);
            float r = 1.f / fmaxf(sqrtf(ss), 1e-12f);
            h[0] = __float2bfloat16(v.x * r);
            h[1] = __float2bfloat16(v.y * r);
            h[2] = __float2bfloat16(v.z * r);
            h[3] = __float2bfloat16(v.w * r);
        }
        *(ushort4*)(Bm + (size_t)row * FDIM + lane * 4) = *(const ushort4*)h;
    }
}

// overwrite the <=1024 present clothes rows with normalized scatter-mean
__global__ void bnorm_present(const float* __restrict__ in, const int* __restrict__ tg,
                              __hip_bfloat16* __restrict__ Bm) {
    int b = blockIdx.x, t = threadIdx.x;
    __shared__ int stg[NBATCH];
    #pragma unroll
    for (int j = 0; j < 4; ++j) stg[t + j * 256] = tg[t + j * 256];
    __syncthreads();
    int c = stg[b];
    bool dup = false;
    #pragma unroll
    for (int j = 0; j < 4; ++j) {
        int i = t + j * 256;
        if (i < b && stg[i] == c) dup = true;
    }
    if (__syncthreads_or(dup)) return;
    __shared__ int mlist[64];
    __shared__ int mcount;
    if (t == 0) mcount = 0;
    __syncthreads();
    #pragma unroll
    for (int j = 0; j < 4; ++j) {
        int i = t + j * 256;
        if (stg[i] == c) { int p = atomicAdd(&mcount, 1); if (p < 64) mlist[p] = i; }
    }
    __syncthreads();
    int n = mcount;
    float v = 0.f;
    for (int i = 0; i < n; ++i) v += in[mlist[i] * FDIM + t];
    v /= (float)n;
    float ss = v * v;
    #pragma unroll
    for (int o = 32; o > 0; o >>= 1) ss += __shfl_xor(ss, o);
    __shared__ float sh[4];
    if ((t & 63) == 0) sh[t >> 6] = ss;
    __syncthreads();
    float tot = sh[0] + sh[1] + sh[2] + sh[3];
    float r = 1.0f / fmaxf(sqrtf(tot), 1e-12f);
    Bm[(size_t)c * FDIM + t] = __float2bfloat16(v * r);
}

// pm [1024][50000] f32 -> maskw [1024][782] u64 (bit l of word w = pm[row][w*64+l] >= 0.5)
// Pure streaming: per wave-chunk, 4 coalesced 256B reads + 4 ballots + one 32B write.
__global__ __launch_bounds__(256)
void pack_kernel(const float* __restrict__ pm, unsigned long long* __restrict__ maskw) {
    const int row = blockIdx.x;
    const int half = blockIdx.y;
    const int wave = threadIdx.x >> 6;
    const int lane = threadIdx.x & 63;
    const float* prow = pm + (size_t)row * NCLOTHES;
    unsigned long long* wrow = maskw + (size_t)row * NWORDS;
    for (int chunk = half * 98 + wave; chunk < half * 98 + 98; chunk += 4) {
        int base = chunk * 256;
        unsigned long long b0, b1, b2, b3;
        {
            int c0 = base + lane;
            float v0 = (c0 < NCLOTHES) ? prow[c0] : 0.f;
            float v1 = (c0 + 64 < NCLOTHES) ? prow[c0 + 64] : 0.f;
            float v2 = (c0 + 128 < NCLOTHES) ? prow[c0 + 128] : 0.f;
            float v3 = (c0 + 192 < NCLOTHES) ? prow[c0 + 192] : 0.f;
            b0 = __ballot(v0 >= 0.5f);
            b1 = __ballot(v1 >= 0.5f);
            b2 = __ballot(v2 >= 0.5f);
            b3 = __ballot(v3 >= 0.5f);
        }
        if (lane < 4) {
            int wi = chunk * 4 + lane;
            unsigned long long w = (lane == 0) ? b0 : (lane == 1) ? b1 : (lane == 2) ? b2 : b3;
            if (wi < NWORDS) wrow[wi] = w;
        }
    }
}

// Fused GEMM (R3 LDS structure) + register-direct mask-bit epilogue.
#define BM 128
#define BN 128
#define BK 32
#define NKSTEP (FDIM / BK)

__global__ __launch_bounds__(256, 4)
void gemm_kernel(const __hip_bfloat16* __restrict__ A, const __hip_bfloat16* __restrict__ Bm,
                 const unsigned long long* __restrict__ maskw,
                 float* __restrict__ partial_ns,      // [NCB2][NBATCH]
                 float* __restrict__ sbuf)            // [NCB2][NBATCH][SLOTS]
{
    __shared__ alignas(16) __hip_bfloat16 As[2][BM * BK];
    __shared__ alignas(16) __hip_bfloat16 Bs[2][BM * BK];

    const int t = threadIdx.x;
    const int bx = blockIdx.x;
    const int bn0 = bx * BN;
    const int bm0 = blockIdx.y * BM;

    const int lane = t & 63;
    const int wave = t >> 6;
    const int wr = wave >> 1, wc = wave & 1;
    const int lrow = lane & 15, lq = lane >> 4;

    const int sr = t >> 2;            // staging row 0..63
    const int sk = (t & 3) * 8;       // staging k chunk

    f32x4 acc[4][4];
    #pragma unroll
    for (int m = 0; m < 4; ++m)
        #pragma unroll
        for (int n = 0; n < 4; ++n) acc[m][n] = (f32x4)0.f;

    // stage k-step 0 into buffer 0
    {
        const __hip_bfloat16* ag = A + (size_t)(bm0 + sr) * FDIM + sk;
        const __hip_bfloat16* bg = Bm + (size_t)(bn0 + sr) * FDIM + sk;
        gload_lds16(ag,             (void*)&As[0][t * 8]);
        gload_lds16(ag + 64 * FDIM, (void*)&As[0][2048 + t * 8]);
        gload_lds16(bg,             (void*)&Bs[0][t * 8]);
        gload_lds16(bg + 64 * FDIM, (void*)&Bs[0][2048 + t * 8]);
    }

    for (int ks = 0; ks < NKSTEP; ++ks) {
        __syncthreads();
        int cur = ks & 1;
        if (ks + 1 < NKSTEP) {
            int nxt = cur ^ 1;
            int k0 = (ks + 1) * BK;
            const __hip_bfloat16* ag = A + (size_t)(bm0 + sr) * FDIM + k0 + sk;
            const __hip_bfloat16* bg = Bm + (size_t)(bn0 + sr) * FDIM + k0 + sk;
            gload_lds16(ag,             (void*)&As[nxt][t * 8]);
            gload_lds16(ag + 64 * FDIM, (void*)&As[nxt][2048 + t * 8]);
            gload_lds16(bg,             (void*)&Bs[nxt][t * 8]);
            gload_lds16(bg + 64 * FDIM, (void*)&Bs[nxt][2048 + t * 8]);
        }
        short8 af[4], bf[4];
        #pragma unroll
        for (int m = 0; m < 4; ++m)
            af[m] = *(const short8*)&As[cur][(wr * 64 + m * 16 + lrow) * BK + lq * 8];
        #pragma unroll
        for (int n = 0; n < 4; ++n)
            bf[n] = *(const short8*)&Bs[cur][(wc * 64 + n * 16 + lrow) * BK + lq * 8];
        #pragma unroll
        for (int m = 0; m < 4; ++m)
            #pragma unroll
            for (int n = 0; n < 4; ++n)
                acc[m][n] = __builtin_amdgcn_mfma_f32_16x16x32_bf16(af[m], bf[n], acc[m][n], 0, 0, 0);
    }

    // ---- epilogue: mask word per (m,r); no pm stream, no atomics, no barriers ----
    // acc C/D layout: tile row = wr*64 + m*16 + lq*4 + r, col = wc*64 + n*16 + lrow
    const int rowbase = bm0 + wr * 64;
    const int colbase = bn0 + wc * 64;
    const int cb2 = bx * 2 + wc;

    unsigned long long mwv[4][4];
    #pragma unroll
    for (int m = 0; m < 4; ++m)
        #pragma unroll
        for (int r = 0; r < 4; ++r) {
            int grow = rowbase + m * 16 + lq * 4 + r;
            mwv[m][r] = maskw[(size_t)grow * NWORDS + cb2];
        }

    #pragma unroll
    for (int m = 0; m < 4; ++m) {
        #pragma unroll
        for (int r = 0; r < 4; ++r) {
            const int grow = rowbase + m * 16 + lq * 4 + r;
            const unsigned long long mw = mwv[m][r];
            float pneg = 0.f;
            #pragma unroll
            for (int n = 0; n < 4; ++n) {
                const int p = n * 16 + lrow;
                bool vld = (colbase + p) < NCLOTHES;
                bool pos = (mw >> p) & 1ull;
                pneg += (vld && !pos) ? __expf(acc[m][n][r]) : 0.f;
            }
            pneg += __shfl_xor(pneg, 1);
            pneg += __shfl_xor(pneg, 2);
            pneg += __shfl_xor(pneg, 4);
            pneg += __shfl_xor(pneg, 8);
            const size_t base = ((size_t)cb2 * NBATCH + grow);
            #pragma unroll
            for (int n = 0; n < 4; ++n) {
                const int p = n * 16 + lrow;
                if ((mw >> p) & 1ull) {
                    int pre = __popcll(mw & ((1ull << p) - 1ull));
                    if (pre < SLOTS) sbuf[base * SLOTS + pre] = acc[m][n][r];
                }
            }
            if (lrow == 0) partial_ns[base] = pneg;
        }
    }
}

// per-row: reduce negsum, popcount mask for npos, finish log terms from slots
__global__ void finish_kernel(const float* __restrict__ partial_ns,
                              const unsigned long long* __restrict__ maskw,
                              const float* __restrict__ sbuf,
                              const int* __restrict__ tg, float* __restrict__ loss_rows) {
    int b = blockIdx.x, t = threadIdx.x;
    int tgt = tg[b];
    const int cbt = tgt >> 6, bitp = tgt & 63;

    // phase 1: negsum
    float ns = 0.f;
    for (int cb = t; cb < NCB2; cb += 256) ns += partial_ns[(size_t)cb * NBATCH + b];
    #pragma unroll
    for (int o = 32; o > 0; o >>= 1) ns += __shfl_xor(ns, o);
    __shared__ float shn[4];
    if ((t & 63) == 0) shn[t >> 6] = ns;
    __syncthreads();
    ns = shn[0] + shn[1] + shn[2] + shn[3];

    // phase 2: scan positives
    float slp = 0.f, idlp = 0.f;
    int np = 0;
    for (int cb = t; cb < NCB2; cb += 256) {
        unsigned long long mw = maskw[(size_t)b * NWORDS + cb];
        int k = __popcll(mw);
        np += k;
        int kk = k < SLOTS ? k : SLOTS;
        const float* sp = sbuf + ((size_t)cb * NBATCH + b) * SLOTS;
        for (int i = 0; i < kk; ++i) {
            float s = sp[i];
            slp += s - __logf(ns + __expf(s));
        }
        if (cb == cbt) {
            int idslot = __popcll(mw & ((1ull << bitp) - 1ull));
            if (idslot < SLOTS) {
                float s = sp[idslot];
                idlp = s - __logf(ns + __expf(s));
            }
        }
    }
    #pragma unroll
    for (int o = 32; o > 0; o >>= 1) {
        slp += __shfl_xor(slp, o);
        idlp += __shfl_xor(idlp, o);
        np += __shfl_xor(np, o);
    }
    __shared__ float sh1[4], sh2[4];
    __shared__ int shp[4];
    if ((t & 63) == 0) { sh1[t >> 6] = slp; sh2[t >> 6] = idlp; shp[t >> 6] = np; }
    __syncthreads();
    if (t == 0) {
        float s_all = sh1[0] + sh1[1] + sh1[2] + sh1[3];
        float i_all = sh2[0] + sh2[1] + sh2[2] + sh2[3];
        int np_all = shp[0] + shp[1] + shp[2] + shp[3];
        loss_rows[b] = -((1.0f - EPSW) * i_all + (EPSW / (float)np_all) * s_all);
    }
}

__global__ void reduce_kernel(const float* __restrict__ lr, float* __restrict__ out) {
    int t = threadIdx.x;
    float s = lr[t] + lr[t + 256] + lr[t + 512] + lr[t + 768];
    #pragma unroll
    for (int o = 32; o > 0; o >>= 1) s += __shfl_xor(s, o);
    __shared__ float sh[4];
    if ((t & 63) == 0) sh[t >> 6] = s;
    __syncthreads();
    if (t == 0) out[0] = (sh[0] + sh[1] + sh[2] + sh[3]) * (1.0f / NBATCH);
}

extern "C" void kernel_launch(void* const* d_in, const int* in_sizes, int n_in,
                              void* d_out, int out_size, void* d_ws, size_t ws_size,
                              hipStream_t stream) {
    const float* inputs  = (const float*)d_in[0];
    const float* fm      = (const float*)d_in[1];
    const float* pmask   = (const float*)d_in[2];
    const int*   targets = (const int*)d_in[3];
    float* out = (float*)d_out;

    char* ws = (char*)d_ws;
    size_t off = 0;
    __hip_bfloat16* A = (__hip_bfloat16*)(ws + off);  off += (size_t)NBATCH * FDIM * 2;        // 512 KB
    __hip_bfloat16* Bm = (__hip_bfloat16*)(ws + off); off += (size_t)CPAD * FDIM * 2;          // 25.6 MB
    off = (off + 255) & ~(size_t)255;
    unsigned long long* maskw = (unsigned long long*)(ws + off); off += (size_t)NBATCH * NWORDS * 8; // 6.4 MB
    float* partial_ns = (float*)(ws + off);        off += (size_t)NCB2 * NBATCH * 4;           // 3.2 MB
    float* sbuf = (float*)(ws + off);              off += (size_t)NCB2 * NBATCH * SLOTS * 4;   // 25.6 MB
    off = (off + 255) & ~(size_t)255;
    float* loss_rows = (float*)(ws + off);         off += 4096;

    anorm_kernel<<<NBATCH, 256, 0, stream>>>(inputs, A);
    bnorm_all<<<2048, 256, 0, stream>>>(fm, Bm);
    bnorm_present<<<NBATCH, 256, 0, stream>>>(inputs, targets, Bm);
    pack_kernel<<<dim3(NBATCH, 2), 256, 0, stream>>>(pmask, maskw);
    gemm_kernel<<<dim3(CPAD / BN, NBATCH / BM), 256, 0, stream>>>(A, Bm, maskw, partial_ns, sbuf);
    finish_kernel<<<NBATCH, 256, 0, stream>>>(partial_ns, maskw, sbuf, targets, loss_rows);
    reduce_kernel<<<1, 256, 0, stream>>>(loss_rows, out);
}